// Round 8
// baseline (137.765 us; speedup 1.0000x reference)
//
#include <hip/hip_runtime.h>
#include <stdint.h>

#define HW 3136
#define HW4 784
#define IMGW 56
#define NIMG 32

static __device__ __forceinline__ int dot4i8(int a, int b, int c) {
#if __has_builtin(__builtin_amdgcn_sdot4)
  return __builtin_amdgcn_sdot4(a, b, c, false);
#else
  c += (int)(int8_t)(a      ) * (int)(int8_t)(b      );
  c += (int)(int8_t)(a >>  8) * (int)(int8_t)(b >>  8);
  c += (int)(int8_t)(a >> 16) * (int)(int8_t)(b >> 16);
  c += (int)(int8_t)(a >> 24) * (int)(int8_t)(b >> 24);
  return c;
#endif
}

// BN: round((alpha*acc + off) * 2^-10), clamp to [-128,127]. Exact f32 ops,
// no contraction (matches numpy mul/add/round-half-even chain bit-exactly).
static __device__ __forceinline__ float bnq(float alpha, float off, int acc) {
  float t = __fmul_rn(alpha, (float)acc);
  t = __fadd_rn(t, off);
  t = __fmul_rn(t, 0x1p-10f);
  float r = rintf(t);
  return fminf(fmaxf(r, -128.0f), 127.0f);
}

// ---------------- prep: pack weights + fold BN constants ----------------
__global__ void prep_kernel(
    const int* __restrict__ s1, const int* __restrict__ m1,
    const float* __restrict__ a1, const float* __restrict__ b1, const int* __restrict__ q1,
    const int* __restrict__ s2, const int* __restrict__ m2,
    const float* __restrict__ a2, const float* __restrict__ b2, const int* __restrict__ q2,
    const int* __restrict__ s3, const int* __restrict__ m3,
    const float* __restrict__ a3, const float* __restrict__ b3, const int* __restrict__ q3,
    int* __restrict__ w1p, int* __restrict__ w2p, int* __restrict__ w3p,
    float* __restrict__ a1p, float* __restrict__ o1p,
    float* __restrict__ a2p, float* __restrict__ o2p,
    float* __restrict__ a3p, float* __restrict__ o3p)
{
  int t = blockIdx.x * blockDim.x + threadIdx.x;
  int nthr = gridDim.x * blockDim.x;

  // w1p[cg*64 + co] packs input channels cg*4..cg*4+3 for output co (conv1: 64x256)
  for (int i = t; i < 64 * 64; i += nthr) {
    int cg = i >> 6, co = i & 63;
    int p = 0;
    for (int j = 0; j < 4; ++j) {
      int ci = cg * 4 + j;
      int idx = co * 256 + ci;
      int w = m1[idx] * (1 << s1[idx]);
      p |= (w & 0xFF) << (8 * j);
    }
    w1p[i] = p;
  }
  // w2p[(tap*16+cg)*64 + co], tap = ky*3+kx (conv2: 64x64x3x3)
  for (int i = t; i < 9 * 16 * 64; i += nthr) {
    int co = i & 63;
    int rest = i >> 6;
    int cg = rest & 15;
    int tap = rest >> 4;
    int ky = tap / 3, kx = tap % 3;
    int p = 0;
    for (int j = 0; j < 4; ++j) {
      int ci = cg * 4 + j;
      int idx = ((co * 64 + ci) * 3 + ky) * 3 + kx;
      int w = m2[idx] * (1 << s2[idx]);
      p |= (w & 0xFF) << (8 * j);
    }
    w2p[i] = p;
  }
  // w3p[(co4*16+cg)*4 + j]: output channel co4*4+j, input group cg (conv3: 256x64)
  for (int i = t; i < 64 * 16 * 4; i += nthr) {
    int j = i & 3;
    int cg = (i >> 2) & 15;
    int co4 = i >> 6;
    int co = co4 * 4 + j;
    int p = 0;
    for (int jj = 0; jj < 4; ++jj) {
      int ci = cg * 4 + jj;
      int idx = co * 64 + ci;
      int w = m3[idx] * (1 << s3[idx]);
      p |= (w & 0xFF) << (8 * jj);
    }
    w3p[i] = p;
  }
  for (int i = t; i < 64; i += nthr) {
    a1p[i] = a1[i];
    o1p[i] = __fmul_rn(b1[i], exp2f((float)q1[i] + 10.0f));
    a2p[i] = a2[i];
    o2p[i] = __fmul_rn(b2[i], exp2f((float)q2[i] + 10.0f));
  }
  for (int i = t; i < 256; i += nthr) {
    a3p[i] = a3[i];
    o3p[i] = __fmul_rn(b3[i], exp2f((float)q3[i] + 10.0f));
  }
}

// ---------------- k0: pack f32 x -> channel-packed int8 x8p[n][pos][256] ----------------
// thread = (pos, o), o = tid&3 (innermost) covers channels o*64..o*64+63.
// All 64 scalar loads issued before any pack (sched_barrier pin) -> 1 round trip.
// Wave writes: 64 lanes x 64 B = 4 KB fully contiguous (no partial-line RMW).
// (sched_barrier kept HERE only: k0 has no compute to overlap, pure MLP win.)
__global__ __launch_bounds__(256) void k0_pack(
    const float* __restrict__ x, int* __restrict__ x8p)
{
  int tid = blockIdx.x * 256 + threadIdx.x;
  int o = tid & 3;
  int pg = tid >> 2;            // global position index: n*HW + pos
  int n = pg / HW;
  int pos = pg - n * HW;

  const float* xb = x + ((size_t)n * 256 + o * 64) * HW + pos;

  float f[64];
#pragma unroll
  for (int k = 0; k < 64; ++k) f[k] = xb[(size_t)k * HW];
  __builtin_amdgcn_sched_barrier(0);  // keep all 64 loads before any consumer

  int4 ov[4];
#pragma unroll
  for (int g = 0; g < 4; ++g) {
    int wds[4];
#pragma unroll
    for (int wdi = 0; wdi < 4; ++wdi) {
      int c0 = g * 16 + wdi * 4;
      wds[wdi] = ((int)f[c0] & 0xFF) | (((int)f[c0 + 1] & 0xFF) << 8) |
                 (((int)f[c0 + 2] & 0xFF) << 16) | (((int)f[c0 + 3] & 0xFF) << 24);
    }
    ov[g].x = wds[0]; ov[g].y = wds[1]; ov[g].z = wds[2]; ov[g].w = wds[3];
  }

  int* ob = x8p + (size_t)pg * 64 + o * 16;
#pragma unroll
  for (int g = 0; g < 4; ++g) ((int4*)ob)[g] = ov[g];
}

// ---------------- k1: conv1 1x1 (256->64) + BN + relu ----------------
// 2 positions/thread (pos, pos+64): weight s_loads shared, 2x dot4 per
// load-wait. Wave s -> out-ch s*16..s*16+15. Grid: 784 blocks x 128 pos.
__global__ __launch_bounds__(256) void k1_conv1(
    const int* __restrict__ x8p,
    const int* __restrict__ w1p,
    const float* __restrict__ a1p, const float* __restrict__ o1p,
    int* __restrict__ y1p)
{
  int lane = threadIdx.x & 63;
  int s = __builtin_amdgcn_readfirstlane(threadIdx.x >> 6);
  int pidx0 = blockIdx.x * 128 + lane;
  int pidx1 = pidx0 + 64;

  const int4* xb0 = (const int4*)(x8p + (size_t)pidx0 * 64);
  const int4* xb1 = (const int4*)(x8p + (size_t)pidx1 * 64);

  int acc0[16], acc1[16];
#pragma unroll
  for (int i = 0; i < 16; ++i) { acc0[i] = 0; acc1[i] = 0; }

#pragma unroll
  for (int q = 0; q < 4; ++q) {  // 4 chunks of 4 int4 per pos (one 64B line each)
    int4 xq0[4], xq1[4];
#pragma unroll
    for (int m = 0; m < 4; ++m) { xq0[m] = xb0[q * 4 + m]; xq1[m] = xb1[q * 4 + m]; }
#pragma unroll
    for (int m = 0; m < 4; ++m) {
#pragma unroll
      for (int e = 0; e < 4; ++e) {
        int xv0 = e == 0 ? xq0[m].x : (e == 1 ? xq0[m].y : (e == 2 ? xq0[m].z : xq0[m].w));
        int xv1 = e == 0 ? xq1[m].x : (e == 1 ? xq1[m].y : (e == 2 ? xq1[m].z : xq1[m].w));
        int cg = q * 16 + m * 4 + e;
        const int4* wr = (const int4*)(w1p + cg * 64 + s * 16);
#pragma unroll
        for (int c = 0; c < 4; ++c) {
          int4 wv = wr[c];
          acc0[c * 4 + 0] = dot4i8(xv0, wv.x, acc0[c * 4 + 0]);
          acc0[c * 4 + 1] = dot4i8(xv0, wv.y, acc0[c * 4 + 1]);
          acc0[c * 4 + 2] = dot4i8(xv0, wv.z, acc0[c * 4 + 2]);
          acc0[c * 4 + 3] = dot4i8(xv0, wv.w, acc0[c * 4 + 3]);
          acc1[c * 4 + 0] = dot4i8(xv1, wv.x, acc1[c * 4 + 0]);
          acc1[c * 4 + 1] = dot4i8(xv1, wv.y, acc1[c * 4 + 1]);
          acc1[c * 4 + 2] = dot4i8(xv1, wv.z, acc1[c * 4 + 2]);
          acc1[c * 4 + 3] = dot4i8(xv1, wv.w, acc1[c * 4 + 3]);
        }
      }
    }
  }

#pragma unroll
  for (int pi = 0; pi < 2; ++pi) {
    const int* acc = pi == 0 ? acc0 : acc1;
    int pidx = pi == 0 ? pidx0 : pidx1;
    int op[4];
#pragma unroll
    for (int c = 0; c < 4; ++c) {
      int p = 0;
#pragma unroll
      for (int j = 0; j < 4; ++j) {
        int co = s * 16 + c * 4 + j;
        float r = bnq(a1p[co], o1p[co], acc[c * 4 + j]);
        int v = (int)r;
        if (v < 0) v = 0;  // relu
        p |= (v & 0xFF) << (8 * j);
      }
      op[c] = p;
    }
    int4 ov; ov.x = op[0]; ov.y = op[1]; ov.z = op[2]; ov.w = op[3];
    *(int4*)(y1p + (size_t)pidx * 16 + s * 4) = ov;
  }
}

// ---------------- k2: conv2 3x3 (64->64, pad 1) + BN + relu ----------------
// 2 ADJACENT positions/thread (w, w+1): 3x3 taps overlap -> per row only
// 4 column vectors (16 int4 loads) feed 1536 dot4s; weights shared per tap.
__global__ __launch_bounds__(256) void k2_conv2(
    const int* __restrict__ y1p,
    const int* __restrict__ w2p,
    const float* __restrict__ a2p, const float* __restrict__ o2p,
    int* __restrict__ y2p)
{
  int lane = threadIdx.x & 63;
  int s = __builtin_amdgcn_readfirstlane(threadIdx.x >> 6);
  int pp = blockIdx.x * 64 + lane;   // pair index
  int n = pp / (HW / 2);
  int rem = pp - n * (HW / 2);
  int h = rem / (IMGW / 2);
  int wp = rem - h * (IMGW / 2);
  int w = wp * 2;                    // even base column; pair = (w, w+1)
  int pos0 = h * IMGW + w;

  int acc0[16], acc1[16];
#pragma unroll
  for (int i = 0; i < 16; ++i) { acc0[i] = 0; acc1[i] = 0; }

  const int* yb = y1p + (size_t)n * HW * 16;

#pragma unroll
  for (int ky = 0; ky < 3; ++ky) {
    int hh = h + ky - 1;
    bool okh = (unsigned)hh < 56u;
    // columns w-1 .. w+2 (c = 0..3)
    int4 xr[4][4];
    int msk[4];
#pragma unroll
    for (int c = 0; c < 4; ++c) {
      int ww = w - 1 + c;
      bool ok = okh && ((unsigned)ww < 56u);
      int pos2 = ok ? (hh * IMGW + ww) : pos0;  // always-valid address
      msk[c] = ok ? -1 : 0;
      const int4* pb = (const int4*)(yb + pos2 * 16);
      xr[c][0] = pb[0];
      xr[c][1] = pb[1];
      xr[c][2] = pb[2];
      xr[c][3] = pb[3];
    }
#pragma unroll
    for (int c = 0; c < 4; ++c) {
      int mk = msk[c];
#pragma unroll
      for (int m = 0; m < 4; ++m) {
        int xs0 = xr[c][m].x & mk;
        int xs1 = xr[c][m].y & mk;
        int xs2 = xr[c][m].z & mk;
        int xs3 = xr[c][m].w & mk;
#pragma unroll
        for (int e = 0; e < 4; ++e) {
          int xv = e == 0 ? xs0 : (e == 1 ? xs1 : (e == 2 ? xs2 : xs3));
          int cg = m * 4 + e;
          // pos0 uses column c as tap kx = c (valid c<3); pos1 as kx = c-1 (valid c>=1)
          if (c < 3) {
            int t = ky * 3 + c;
            const int4* wr = (const int4*)(w2p + (t * 16 + cg) * 64 + s * 16);
#pragma unroll
            for (int cc = 0; cc < 4; ++cc) {
              int4 wv = wr[cc];
              acc0[cc * 4 + 0] = dot4i8(xv, wv.x, acc0[cc * 4 + 0]);
              acc0[cc * 4 + 1] = dot4i8(xv, wv.y, acc0[cc * 4 + 1]);
              acc0[cc * 4 + 2] = dot4i8(xv, wv.z, acc0[cc * 4 + 2]);
              acc0[cc * 4 + 3] = dot4i8(xv, wv.w, acc0[cc * 4 + 3]);
            }
          }
          if (c >= 1) {
            int t = ky * 3 + (c - 1);
            const int4* wr = (const int4*)(w2p + (t * 16 + cg) * 64 + s * 16);
#pragma unroll
            for (int cc = 0; cc < 4; ++cc) {
              int4 wv = wr[cc];
              acc1[cc * 4 + 0] = dot4i8(xv, wv.x, acc1[cc * 4 + 0]);
              acc1[cc * 4 + 1] = dot4i8(xv, wv.y, acc1[cc * 4 + 1]);
              acc1[cc * 4 + 2] = dot4i8(xv, wv.z, acc1[cc * 4 + 2]);
              acc1[cc * 4 + 3] = dot4i8(xv, wv.w, acc1[cc * 4 + 3]);
            }
          }
        }
      }
    }
  }

#pragma unroll
  for (int pi = 0; pi < 2; ++pi) {
    const int* acc = pi == 0 ? acc0 : acc1;
    int pos = pos0 + pi;
    int op[4];
#pragma unroll
    for (int c = 0; c < 4; ++c) {
      int p = 0;
#pragma unroll
      for (int j = 0; j < 4; ++j) {
        int co = s * 16 + c * 4 + j;
        float r = bnq(a2p[co], o2p[co], acc[c * 4 + j]);
        int v = (int)r;
        if (v < 0) v = 0;
        p |= (v & 0xFF) << (8 * j);
      }
      op[c] = p;
    }
    int4 ov; ov.x = op[0]; ov.y = op[1]; ov.z = op[2]; ov.w = op[3];
    *(int4*)(y2p + ((size_t)n * HW + pos) * 16 + s * 4) = ov;
  }
}

// ---------------- k3: conv3 1x1 (64->256) + BN + residual + relu ----------------
// Wave s computes out-ch 64s..64s+63 (co4 = s*16..s*16+15).
__global__ __launch_bounds__(256) void k3_conv3(
    const int* __restrict__ y2p,
    const int* __restrict__ w3p,
    const float* __restrict__ a3p, const float* __restrict__ o3p,
    const int* __restrict__ x8p,
    float* __restrict__ out)
{
  int lane = threadIdx.x & 63;
  int s = __builtin_amdgcn_readfirstlane(threadIdx.x >> 6);
  int pidx = blockIdx.x * 64 + lane;
  int n = pidx / HW;
  int pos = pidx - n * HW;

  // y2 activation vector: 64B = 4 dwordx4
  const int4* yb4 = (const int4*)(y2p + (size_t)pidx * 16);
  int4 xq[4];
#pragma unroll
  for (int m = 0; m < 4; ++m) xq[m] = yb4[m];

  // residual slice for this wave's 64 channels: 4 dwordx4
  const int4* rb4 = (const int4*)(x8p + (size_t)pidx * 64 + s * 16);
  int4 rq[4];
#pragma unroll
  for (int m = 0; m < 4; ++m) rq[m] = rb4[m];

  int xp[16];
#pragma unroll
  for (int m = 0; m < 4; ++m) {
    xp[m * 4 + 0] = xq[m].x;
    xp[m * 4 + 1] = xq[m].y;
    xp[m * 4 + 2] = xq[m].z;
    xp[m * 4 + 3] = xq[m].w;
  }
  int rv[16];
#pragma unroll
  for (int m = 0; m < 4; ++m) {
    rv[m * 4 + 0] = rq[m].x;
    rv[m * 4 + 1] = rq[m].y;
    rv[m * 4 + 2] = rq[m].z;
    rv[m * 4 + 3] = rq[m].w;
  }

#pragma unroll
  for (int c4 = 0; c4 < 16; ++c4) {
    int co4 = s * 16 + c4;
    const int4* wr = ((const int4*)w3p) + co4 * 16;  // uniform -> s_load
    int ac0 = 0, ac1 = 0, ac2 = 0, ac3 = 0;
#pragma unroll
    for (int cg = 0; cg < 16; ++cg) {
      int4 wv = wr[cg];
      ac0 = dot4i8(xp[cg], wv.x, ac0);
      ac1 = dot4i8(xp[cg], wv.y, ac1);
      ac2 = dot4i8(xp[cg], wv.z, ac2);
      ac3 = dot4i8(xp[cg], wv.w, ac3);
    }

    int ip = rv[c4];
    int ids[4];
    ids[0] = (int)(int8_t)(ip);
    ids[1] = (int)(int8_t)(ip >> 8);
    ids[2] = (int)(int8_t)(ip >> 16);
    ids[3] = (int)(int8_t)(ip >> 24);

    float* ob = out + ((size_t)n * 256 + (size_t)co4 * 4) * HW + pos;
    int accs[4] = {ac0, ac1, ac2, ac3};
#pragma unroll
    for (int j = 0; j < 4; ++j) {
      int co = co4 * 4 + j;
      float r = bnq(a3p[co], o3p[co], accs[j]);
      int v = (int)r + ids[j];
      v = v > 127 ? 127 : v;
      v = v < 0 ? 0 : v;  // clamp(-128,..) then relu => max(0, min(127, .))
      ob[(size_t)j * HW] = (float)v;
    }
  }
}

extern "C" void kernel_launch(void* const* d_in, const int* in_sizes, int n_in,
                              void* d_out, int out_size, void* d_ws, size_t ws_size,
                              hipStream_t stream) {
  const float* x  = (const float*)d_in[0];
  const int*   s1 = (const int*)d_in[1];
  const int*   m1 = (const int*)d_in[2];
  const float* a1 = (const float*)d_in[3];
  const float* b1 = (const float*)d_in[4];
  const int*   q1 = (const int*)d_in[5];
  const int*   s2 = (const int*)d_in[6];
  const int*   m2 = (const int*)d_in[7];
  const float* a2 = (const float*)d_in[8];
  const float* b2 = (const float*)d_in[9];
  const int*   q2 = (const int*)d_in[10];
  const int*   s3 = (const int*)d_in[11];
  const int*   m3 = (const int*)d_in[12];
  const float* a3 = (const float*)d_in[13];
  const float* b3 = (const float*)d_in[14];
  const int*   q3 = (const int*)d_in[15];

  char* ws = (char*)d_ws;
  int* w1p = (int*)(ws + 0);        // 16384 B
  int* w2p = (int*)(ws + 16384);    // 36864 B
  int* w3p = (int*)(ws + 53248);    // 16384 B
  float* a1p = (float*)(ws + 69632);
  float* o1p = (float*)(ws + 69888);
  float* a2p = (float*)(ws + 70144);
  float* o2p = (float*)(ws + 70400);
  float* a3p = (float*)(ws + 70656);
  float* o3p = (float*)(ws + 71680);
  int* y1p = (int*)(ws + 73728);                       // 6,422,528 B (packed [n][pos][16])
  int* y2p = (int*)(ws + 73728 + 6422528);             // 6,422,528 B (packed)
  int* x8p = (int*)(ws + 73728 + 2 * 6422528);         // 25,690,112 B (packed [n][pos][64])

  prep_kernel<<<64, 256, 0, stream>>>(s1, m1, a1, b1, q1,
                                      s2, m2, a2, b2, q2,
                                      s3, m3, a3, b3, q3,
                                      w1p, w2p, w3p,
                                      a1p, o1p, a2p, o2p, a3p, o3p);

  {
    int total = 4 * NIMG * HW;  // (pos, o) threads
    k0_pack<<<(total + 255) / 256, 256, 0, stream>>>(x, x8p);
  }

  // k1/k2: 2 positions per thread -> 784 blocks; k3: 1 pos/thread -> 1568.
  k1_conv1<<<(NIMG * HW) / 128, 256, 0, stream>>>(x8p, w1p, a1p, o1p, y1p);
  k2_conv2<<<(NIMG * HW / 2) / 64, 256, 0, stream>>>(y1p, w2p, a2p, o2p, y2p);
  k3_conv3<<<(NIMG * HW) / 64, 256, 0, stream>>>(y2p, w3p, a3p, o3p, x8p,
                                                 (float*)d_out);
}

// Round 9
// 127.117 us; speedup vs baseline: 1.0838x; 1.0838x over previous
//
#include <hip/hip_runtime.h>
#include <stdint.h>

#define HW 3136
#define IMGW 56
#define NIMG 32

static __device__ __forceinline__ int dot4i8(int a, int b, int c) {
#if __has_builtin(__builtin_amdgcn_sdot4)
  return __builtin_amdgcn_sdot4(a, b, c, false);
#else
  c += (int)(int8_t)(a      ) * (int)(int8_t)(b      );
  c += (int)(int8_t)(a >>  8) * (int)(int8_t)(b >>  8);
  c += (int)(int8_t)(a >> 16) * (int)(int8_t)(b >> 16);
  c += (int)(int8_t)(a >> 24) * (int)(int8_t)(b >> 24);
  return c;
#endif
}

// BN: round((alpha*acc + off) * 2^-10), clamp to [-128,127]. Exact f32 ops,
// no contraction (matches numpy mul/add/round-half-even chain bit-exactly).
static __device__ __forceinline__ float bnq(float alpha, float off, int acc) {
  float t = __fmul_rn(alpha, (float)acc);
  t = __fadd_rn(t, off);
  t = __fmul_rn(t, 0x1p-10f);
  float r = rintf(t);
  return fminf(fmaxf(r, -128.0f), 127.0f);
}

// ---------------- prep: pack weights + fold BN constants ----------------
__global__ void prep_kernel(
    const int* __restrict__ s1, const int* __restrict__ m1,
    const float* __restrict__ a1, const float* __restrict__ b1, const int* __restrict__ q1,
    const int* __restrict__ s2, const int* __restrict__ m2,
    const float* __restrict__ a2, const float* __restrict__ b2, const int* __restrict__ q2,
    const int* __restrict__ s3, const int* __restrict__ m3,
    const float* __restrict__ a3, const float* __restrict__ b3, const int* __restrict__ q3,
    int* __restrict__ w1p, int* __restrict__ w2p, int* __restrict__ w3p,
    float* __restrict__ a1p, float* __restrict__ o1p,
    float* __restrict__ a2p, float* __restrict__ o2p,
    float* __restrict__ a3p, float* __restrict__ o3p)
{
  int t = blockIdx.x * blockDim.x + threadIdx.x;
  int nthr = gridDim.x * blockDim.x;

  // w1p[cg*64 + co] packs input channels cg*4..cg*4+3 for output co (conv1: 64x256)
  for (int i = t; i < 64 * 64; i += nthr) {
    int cg = i >> 6, co = i & 63;
    int p = 0;
    for (int j = 0; j < 4; ++j) {
      int ci = cg * 4 + j;
      int idx = co * 256 + ci;
      int w = m1[idx] * (1 << s1[idx]);
      p |= (w & 0xFF) << (8 * j);
    }
    w1p[i] = p;
  }
  // w2p NEW layout: i = ((s*9+tap)*16+cg)*16 + cc*4 + j
  // -> per (s,tap) the 16x4 int4 weight block is 256B contiguous (s_load runs).
  for (int i = t; i < 4 * 9 * 16 * 16; i += nthr) {
    int j = i & 3;
    int cc = (i >> 2) & 3;
    int cg = (i >> 4) & 15;
    int rest = i >> 8;        // s*9 + tap
    int tap = rest % 9;
    int s = rest / 9;
    int co = s * 16 + cc * 4 + j;
    int ky = tap / 3, kx = tap % 3;
    int p = 0;
    for (int jj = 0; jj < 4; ++jj) {
      int ci = cg * 4 + jj;
      int idx = ((co * 64 + ci) * 3 + ky) * 3 + kx;
      int w = m2[idx] * (1 << s2[idx]);
      p |= (w & 0xFF) << (8 * jj);
    }
    w2p[i] = p;
  }
  // w3p[(co4*16+cg)*4 + j]: output channel co4*4+j, input group cg (conv3: 256x64)
  for (int i = t; i < 64 * 16 * 4; i += nthr) {
    int j = i & 3;
    int cg = (i >> 2) & 15;
    int co4 = i >> 6;
    int co = co4 * 4 + j;
    int p = 0;
    for (int jj = 0; jj < 4; ++jj) {
      int ci = cg * 4 + jj;
      int idx = co * 64 + ci;
      int w = m3[idx] * (1 << s3[idx]);
      p |= (w & 0xFF) << (8 * jj);
    }
    w3p[i] = p;
  }
  for (int i = t; i < 64; i += nthr) {
    a1p[i] = a1[i];
    o1p[i] = __fmul_rn(b1[i], exp2f((float)q1[i] + 10.0f));
    a2p[i] = a2[i];
    o2p[i] = __fmul_rn(b2[i], exp2f((float)q2[i] + 10.0f));
  }
  for (int i = t; i < 256; i += nthr) {
    a3p[i] = a3[i];
    o3p[i] = __fmul_rn(b3[i], exp2f((float)q3[i] + 10.0f));
  }
}

// ---------------- k0: pack f32 x -> channel-packed int8 x8p[n][pos][256] ----------------
// thread = (pos, o), o = tid&3 (innermost) covers channels o*64..o*64+63.
// All 64 scalar loads issued before any pack (sched_barrier pin) -> 1 round trip.
// Wave writes: 64 lanes x 64 B = 4 KB fully contiguous (no partial-line RMW).
// (sched_barrier kept HERE only: k0 has no compute to overlap, pure MLP win.)
__global__ __launch_bounds__(256) void k0_pack(
    const float* __restrict__ x, int* __restrict__ x8p)
{
  int tid = blockIdx.x * 256 + threadIdx.x;
  int o = tid & 3;
  int pg = tid >> 2;            // global position index: n*HW + pos
  int n = pg / HW;
  int pos = pg - n * HW;

  const float* xb = x + ((size_t)n * 256 + o * 64) * HW + pos;

  float f[64];
#pragma unroll
  for (int k = 0; k < 64; ++k) f[k] = xb[(size_t)k * HW];
  __builtin_amdgcn_sched_barrier(0);  // keep all 64 loads before any consumer

  int4 ov[4];
#pragma unroll
  for (int g = 0; g < 4; ++g) {
    int wds[4];
#pragma unroll
    for (int wdi = 0; wdi < 4; ++wdi) {
      int c0 = g * 16 + wdi * 4;
      wds[wdi] = ((int)f[c0] & 0xFF) | (((int)f[c0 + 1] & 0xFF) << 8) |
                 (((int)f[c0 + 2] & 0xFF) << 16) | (((int)f[c0 + 3] & 0xFF) << 24);
    }
    ov[g].x = wds[0]; ov[g].y = wds[1]; ov[g].z = wds[2]; ov[g].w = wds[3];
  }

  int* ob = x8p + (size_t)pg * 64 + o * 16;
#pragma unroll
  for (int g = 0; g < 4; ++g) ((int4*)ob)[g] = ov[g];
}

// ---------------- k1: conv1 1x1 (256->64) + BN + relu ----------------
// 2 positions/thread (pos, pos+64): weight s_loads shared, 2x dot4 per
// load-wait. Wave s -> out-ch s*16..s*16+15. Grid: 784 blocks x 128 pos.
__global__ __launch_bounds__(256) void k1_conv1(
    const int* __restrict__ x8p,
    const int* __restrict__ w1p,
    const float* __restrict__ a1p, const float* __restrict__ o1p,
    int* __restrict__ y1p)
{
  int lane = threadIdx.x & 63;
  int s = __builtin_amdgcn_readfirstlane(threadIdx.x >> 6);
  int pidx0 = blockIdx.x * 128 + lane;
  int pidx1 = pidx0 + 64;

  const int4* xb0 = (const int4*)(x8p + (size_t)pidx0 * 64);
  const int4* xb1 = (const int4*)(x8p + (size_t)pidx1 * 64);

  int acc0[16], acc1[16];
#pragma unroll
  for (int i = 0; i < 16; ++i) { acc0[i] = 0; acc1[i] = 0; }

#pragma unroll
  for (int q = 0; q < 4; ++q) {  // 4 chunks of 4 int4 per pos (one 64B line each)
    int4 xq0[4], xq1[4];
#pragma unroll
    for (int m = 0; m < 4; ++m) { xq0[m] = xb0[q * 4 + m]; xq1[m] = xb1[q * 4 + m]; }
#pragma unroll
    for (int m = 0; m < 4; ++m) {
#pragma unroll
      for (int e = 0; e < 4; ++e) {
        int xv0 = e == 0 ? xq0[m].x : (e == 1 ? xq0[m].y : (e == 2 ? xq0[m].z : xq0[m].w));
        int xv1 = e == 0 ? xq1[m].x : (e == 1 ? xq1[m].y : (e == 2 ? xq1[m].z : xq1[m].w));
        int cg = q * 16 + m * 4 + e;
        const int4* wr = (const int4*)(w1p + cg * 64 + s * 16);
#pragma unroll
        for (int c = 0; c < 4; ++c) {
          int4 wv = wr[c];
          acc0[c * 4 + 0] = dot4i8(xv0, wv.x, acc0[c * 4 + 0]);
          acc0[c * 4 + 1] = dot4i8(xv0, wv.y, acc0[c * 4 + 1]);
          acc0[c * 4 + 2] = dot4i8(xv0, wv.z, acc0[c * 4 + 2]);
          acc0[c * 4 + 3] = dot4i8(xv0, wv.w, acc0[c * 4 + 3]);
          acc1[c * 4 + 0] = dot4i8(xv1, wv.x, acc1[c * 4 + 0]);
          acc1[c * 4 + 1] = dot4i8(xv1, wv.y, acc1[c * 4 + 1]);
          acc1[c * 4 + 2] = dot4i8(xv1, wv.z, acc1[c * 4 + 2]);
          acc1[c * 4 + 3] = dot4i8(xv1, wv.w, acc1[c * 4 + 3]);
        }
      }
    }
  }

#pragma unroll
  for (int pi = 0; pi < 2; ++pi) {
    const int* acc = pi == 0 ? acc0 : acc1;
    int pidx = pi == 0 ? pidx0 : pidx1;
    int op[4];
#pragma unroll
    for (int c = 0; c < 4; ++c) {
      int p = 0;
#pragma unroll
      for (int j = 0; j < 4; ++j) {
        int co = s * 16 + c * 4 + j;
        float r = bnq(a1p[co], o1p[co], acc[c * 4 + j]);
        int v = (int)r;
        if (v < 0) v = 0;  // relu
        p |= (v & 0xFF) << (8 * j);
      }
      op[c] = p;
    }
    int4 ov; ov.x = op[0]; ov.y = op[1]; ov.z = op[2]; ov.w = op[3];
    *(int4*)(y1p + (size_t)pidx * 16 + s * 4) = ov;
  }
}

// ---------------- k2: conv2 3x3 (64->64, pad 1) + BN + relu ----------------
// LDS-staged halo tile: block = 64 consecutive positions (exactly 2 image
// rows since 3136 = 49*64). Stage [4 rows][58 cols][16 ints] zero-padded
// (rows h0-1..h0+2, cols -1..56) -> inner loop has NO masks: per tap just
// 4 ds_read_b128 + 256 dot4. Lane stride 64B -> 2-way bank alias (free).
__global__ __launch_bounds__(256) void k2_conv2(
    const int* __restrict__ y1p,
    const int* __restrict__ w2p,   // [s][tap][cg][cc]: ((s*9+t)*16+cg)*16+cc*4+j
    const float* __restrict__ a2p, const float* __restrict__ o2p,
    int* __restrict__ y2p)
{
  __shared__ int4 lds[4 * 58 * 4];   // 928 int4 = 14848 B

  int lane = threadIdx.x & 63;
  int s = __builtin_amdgcn_readfirstlane(threadIdx.x >> 6);
  int p0 = blockIdx.x * 64;          // tile start (global pos units)
  int n = p0 / HW;
  int p0l = p0 - n * HW;             // tile start within image
  int h0 = p0l / IMGW;               // first image row of tile

  // ---- stage: rows h0-1..h0+2, padded cols (0 and 57 zero) ----
  const int4* src = (const int4*)y1p;
  int tid = threadIdx.x;
#pragma unroll
  for (int i = 0; i < 4; ++i) {
    int idx = tid + i * 256;
    if (idx < 928) {
      int pp = idx >> 2;             // padded pos 0..231
      int chunk = idx & 3;
      int r = pp / 58;
      int col = pp - r * 58;
      int hh = h0 - 1 + r;
      int4 v = make_int4(0, 0, 0, 0);
      if ((unsigned)hh < 56u && col >= 1 && col <= 56) {
        v = src[((size_t)n * HW + (size_t)hh * IMGW + (col - 1)) * 4 + chunk];
      }
      lds[idx] = v;
    }
  }
  __syncthreads();

  int posl = p0l + lane;
  int h = posl / IMGW;
  int w = posl - h * IMGW;
  int center = (h - h0 + 1) * 58 + (w + 1);  // padded pos of this lane

  int acc[16];
#pragma unroll
  for (int i = 0; i < 16; ++i) acc[i] = 0;

  const int4* wq = (const int4*)w2p;

#pragma unroll
  for (int ky = 0; ky < 3; ++ky) {
#pragma unroll
    for (int kx = 0; kx < 3; ++kx) {
      int t = ky * 3 + kx;
      int lp2 = center + (ky - 1) * 58 + (kx - 1);
      const int4* xt = &lds[lp2 * 4];
      int4 x0 = xt[0], x1 = xt[1], x2 = xt[2], x3 = xt[3];
      const int4* wt = wq + (s * 9 + t) * 64;  // 16 cg x 4 cc int4, contiguous
#pragma unroll
      for (int m = 0; m < 4; ++m) {
        int4 xm = m == 0 ? x0 : (m == 1 ? x1 : (m == 2 ? x2 : x3));
#pragma unroll
        for (int e = 0; e < 4; ++e) {
          int xv = e == 0 ? xm.x : (e == 1 ? xm.y : (e == 2 ? xm.z : xm.w));
          const int4* wr = wt + (m * 4 + e) * 4;
#pragma unroll
          for (int cc = 0; cc < 4; ++cc) {
            int4 wv = wr[cc];
            acc[cc * 4 + 0] = dot4i8(xv, wv.x, acc[cc * 4 + 0]);
            acc[cc * 4 + 1] = dot4i8(xv, wv.y, acc[cc * 4 + 1]);
            acc[cc * 4 + 2] = dot4i8(xv, wv.z, acc[cc * 4 + 2]);
            acc[cc * 4 + 3] = dot4i8(xv, wv.w, acc[cc * 4 + 3]);
          }
        }
      }
    }
  }

  int op[4];
#pragma unroll
  for (int c = 0; c < 4; ++c) {
    int p = 0;
#pragma unroll
    for (int j = 0; j < 4; ++j) {
      int co = s * 16 + c * 4 + j;
      float r = bnq(a2p[co], o2p[co], acc[c * 4 + j]);
      int v = (int)r;
      if (v < 0) v = 0;
      p |= (v & 0xFF) << (8 * j);
    }
    op[c] = p;
  }
  int4 ov; ov.x = op[0]; ov.y = op[1]; ov.z = op[2]; ov.w = op[3];
  *(int4*)(y2p + (size_t)(p0 + lane) * 16 + s * 4) = ov;
}

// ---------------- k3: conv3 1x1 (64->256) + BN + residual + relu ----------------
// Wave s computes out-ch 64s..64s+63 (co4 = s*16..s*16+15).
__global__ __launch_bounds__(256) void k3_conv3(
    const int* __restrict__ y2p,
    const int* __restrict__ w3p,
    const float* __restrict__ a3p, const float* __restrict__ o3p,
    const int* __restrict__ x8p,
    float* __restrict__ out)
{
  int lane = threadIdx.x & 63;
  int s = __builtin_amdgcn_readfirstlane(threadIdx.x >> 6);
  int pidx = blockIdx.x * 64 + lane;
  int n = pidx / HW;
  int pos = pidx - n * HW;

  // y2 activation vector: 64B = 4 dwordx4
  const int4* yb4 = (const int4*)(y2p + (size_t)pidx * 16);
  int4 xq[4];
#pragma unroll
  for (int m = 0; m < 4; ++m) xq[m] = yb4[m];

  // residual slice for this wave's 64 channels: 4 dwordx4
  const int4* rb4 = (const int4*)(x8p + (size_t)pidx * 64 + s * 16);
  int4 rq[4];
#pragma unroll
  for (int m = 0; m < 4; ++m) rq[m] = rb4[m];

  int xp[16];
#pragma unroll
  for (int m = 0; m < 4; ++m) {
    xp[m * 4 + 0] = xq[m].x;
    xp[m * 4 + 1] = xq[m].y;
    xp[m * 4 + 2] = xq[m].z;
    xp[m * 4 + 3] = xq[m].w;
  }
  int rv[16];
#pragma unroll
  for (int m = 0; m < 4; ++m) {
    rv[m * 4 + 0] = rq[m].x;
    rv[m * 4 + 1] = rq[m].y;
    rv[m * 4 + 2] = rq[m].z;
    rv[m * 4 + 3] = rq[m].w;
  }

#pragma unroll
  for (int c4 = 0; c4 < 16; ++c4) {
    int co4 = s * 16 + c4;
    const int4* wr = ((const int4*)w3p) + co4 * 16;  // uniform -> s_load
    int ac0 = 0, ac1 = 0, ac2 = 0, ac3 = 0;
#pragma unroll
    for (int cg = 0; cg < 16; ++cg) {
      int4 wv = wr[cg];
      ac0 = dot4i8(xp[cg], wv.x, ac0);
      ac1 = dot4i8(xp[cg], wv.y, ac1);
      ac2 = dot4i8(xp[cg], wv.z, ac2);
      ac3 = dot4i8(xp[cg], wv.w, ac3);
    }

    int ip = rv[c4];
    int ids[4];
    ids[0] = (int)(int8_t)(ip);
    ids[1] = (int)(int8_t)(ip >> 8);
    ids[2] = (int)(int8_t)(ip >> 16);
    ids[3] = (int)(int8_t)(ip >> 24);

    float* ob = out + ((size_t)n * 256 + (size_t)co4 * 4) * HW + pos;
    int accs[4] = {ac0, ac1, ac2, ac3};
#pragma unroll
    for (int j = 0; j < 4; ++j) {
      int co = co4 * 4 + j;
      float r = bnq(a3p[co], o3p[co], accs[j]);
      int v = (int)r + ids[j];
      v = v > 127 ? 127 : v;
      v = v < 0 ? 0 : v;  // clamp(-128,..) then relu => max(0, min(127, .))
      ob[(size_t)j * HW] = (float)v;
    }
  }
}

extern "C" void kernel_launch(void* const* d_in, const int* in_sizes, int n_in,
                              void* d_out, int out_size, void* d_ws, size_t ws_size,
                              hipStream_t stream) {
  const float* x  = (const float*)d_in[0];
  const int*   s1 = (const int*)d_in[1];
  const int*   m1 = (const int*)d_in[2];
  const float* a1 = (const float*)d_in[3];
  const float* b1 = (const float*)d_in[4];
  const int*   q1 = (const int*)d_in[5];
  const int*   s2 = (const int*)d_in[6];
  const int*   m2 = (const int*)d_in[7];
  const float* a2 = (const float*)d_in[8];
  const float* b2 = (const float*)d_in[9];
  const int*   q2 = (const int*)d_in[10];
  const int*   s3 = (const int*)d_in[11];
  const int*   m3 = (const int*)d_in[12];
  const float* a3 = (const float*)d_in[13];
  const float* b3 = (const float*)d_in[14];
  const int*   q3 = (const int*)d_in[15];

  char* ws = (char*)d_ws;
  int* w1p = (int*)(ws + 0);        // 16384 B
  int* w2p = (int*)(ws + 16384);    // 36864 B
  int* w3p = (int*)(ws + 53248);    // 16384 B
  float* a1p = (float*)(ws + 69632);
  float* o1p = (float*)(ws + 69888);
  float* a2p = (float*)(ws + 70144);
  float* o2p = (float*)(ws + 70400);
  float* a3p = (float*)(ws + 70656);
  float* o3p = (float*)(ws + 71680);
  int* y1p = (int*)(ws + 73728);                       // 6,422,528 B (packed [n][pos][16])
  int* y2p = (int*)(ws + 73728 + 6422528);             // 6,422,528 B (packed)
  int* x8p = (int*)(ws + 73728 + 2 * 6422528);         // 25,690,112 B (packed [n][pos][64])

  prep_kernel<<<64, 256, 0, stream>>>(s1, m1, a1, b1, q1,
                                      s2, m2, a2, b2, q2,
                                      s3, m3, a3, b3, q3,
                                      w1p, w2p, w3p,
                                      a1p, o1p, a2p, o2p, a3p, o3p);

  {
    int total = 4 * NIMG * HW;  // (pos, o) threads
    k0_pack<<<(total + 255) / 256, 256, 0, stream>>>(x, x8p);
  }

  k1_conv1<<<(NIMG * HW) / 128, 256, 0, stream>>>(x8p, w1p, a1p, o1p, y1p);
  k2_conv2<<<(NIMG * HW) / 64, 256, 0, stream>>>(y1p, w2p, a2p, o2p, y2p);
  k3_conv3<<<(NIMG * HW) / 64, 256, 0, stream>>>(y2p, w3p, a3p, o3p, x8p,
                                                 (float*)d_out);
}

// Round 10
// 116.390 us; speedup vs baseline: 1.1837x; 1.0922x over previous
//
#include <hip/hip_runtime.h>
#include <stdint.h>

#define HW 3136
#define IMGW 56
#define NIMG 32

static __device__ __forceinline__ int dot4i8(int a, int b, int c) {
#if __has_builtin(__builtin_amdgcn_sdot4)
  return __builtin_amdgcn_sdot4(a, b, c, false);
#else
  c += (int)(int8_t)(a      ) * (int)(int8_t)(b      );
  c += (int)(int8_t)(a >>  8) * (int)(int8_t)(b >>  8);
  c += (int)(int8_t)(a >> 16) * (int)(int8_t)(b >> 16);
  c += (int)(int8_t)(a >> 24) * (int)(int8_t)(b >> 24);
  return c;
#endif
}

// BN: round((alpha*acc + off) * 2^-10), clamp to [-128,127]. Exact f32 ops,
// no contraction (matches numpy mul/add/round-half-even chain bit-exactly).
static __device__ __forceinline__ float bnq(float alpha, float off, int acc) {
  float t = __fmul_rn(alpha, (float)acc);
  t = __fadd_rn(t, off);
  t = __fmul_rn(t, 0x1p-10f);
  float r = rintf(t);
  return fminf(fmaxf(r, -128.0f), 127.0f);
}

// ---------------- prep: pack weights + fold BN constants ----------------
__global__ void prep_kernel(
    const int* __restrict__ s1, const int* __restrict__ m1,
    const float* __restrict__ a1, const float* __restrict__ b1, const int* __restrict__ q1,
    const int* __restrict__ s2, const int* __restrict__ m2,
    const float* __restrict__ a2, const float* __restrict__ b2, const int* __restrict__ q2,
    const int* __restrict__ s3, const int* __restrict__ m3,
    const float* __restrict__ a3, const float* __restrict__ b3, const int* __restrict__ q3,
    int* __restrict__ w1p, int* __restrict__ w2p, int* __restrict__ w3p,
    float* __restrict__ a1p, float* __restrict__ o1p,
    float* __restrict__ a2p, float* __restrict__ o2p,
    float* __restrict__ a3p, float* __restrict__ o3p)
{
  int t = blockIdx.x * blockDim.x + threadIdx.x;
  int nthr = gridDim.x * blockDim.x;

  // w1p[cg*64 + co] packs input channels cg*4..cg*4+3 for output co (conv1: 64x256)
  for (int i = t; i < 64 * 64; i += nthr) {
    int cg = i >> 6, co = i & 63;
    int p = 0;
    for (int j = 0; j < 4; ++j) {
      int ci = cg * 4 + j;
      int idx = co * 256 + ci;
      int w = m1[idx] * (1 << s1[idx]);
      p |= (w & 0xFF) << (8 * j);
    }
    w1p[i] = p;
  }
  // w2p layout: i = ((s*9+tap)*16+cg)*16 + cc*4 + j
  // -> per (s,tap) the 16x4 int4 weight block is 256B contiguous (s_load runs).
  for (int i = t; i < 4 * 9 * 16 * 16; i += nthr) {
    int j = i & 3;
    int cc = (i >> 2) & 3;
    int cg = (i >> 4) & 15;
    int rest = i >> 8;        // s*9 + tap
    int tap = rest % 9;
    int s = rest / 9;
    int co = s * 16 + cc * 4 + j;
    int ky = tap / 3, kx = tap % 3;
    int p = 0;
    for (int jj = 0; jj < 4; ++jj) {
      int ci = cg * 4 + jj;
      int idx = ((co * 64 + ci) * 3 + ky) * 3 + kx;
      int w = m2[idx] * (1 << s2[idx]);
      p |= (w & 0xFF) << (8 * jj);
    }
    w2p[i] = p;
  }
  // w3p[(co4*16+cg)*4 + j]: output channel co4*4+j, input group cg (conv3: 256x64)
  for (int i = t; i < 64 * 16 * 4; i += nthr) {
    int j = i & 3;
    int cg = (i >> 2) & 15;
    int co4 = i >> 6;
    int co = co4 * 4 + j;
    int p = 0;
    for (int jj = 0; jj < 4; ++jj) {
      int ci = cg * 4 + jj;
      int idx = co * 64 + ci;
      int w = m3[idx] * (1 << s3[idx]);
      p |= (w & 0xFF) << (8 * jj);
    }
    w3p[i] = p;
  }
  for (int i = t; i < 64; i += nthr) {
    a1p[i] = a1[i];
    o1p[i] = __fmul_rn(b1[i], exp2f((float)q1[i] + 10.0f));
    a2p[i] = a2[i];
    o2p[i] = __fmul_rn(b2[i], exp2f((float)q2[i] + 10.0f));
  }
  for (int i = t; i < 256; i += nthr) {
    a3p[i] = a3[i];
    o3p[i] = __fmul_rn(b3[i], exp2f((float)q3[i] + 10.0f));
  }
}

// ---------------- k01: pack x -> int8 (global x8p + LDS) then conv1 ----------------
// Phase A (k0 pattern): thread = (p=tid>>2, o=tid&3); 64 strided scalar loads
// pinned ahead of packing; writes x8p coalesced (4 lanes cover a 64B line)
// AND the LDS tile [64 pos][68-int padded row] (stride 68 -> phase-B b128
// reads spread over 8 banks instead of 1).
// Phase B (conv1): remap to (lane=pos, wave s -> out-ch s*16..s*16+15);
// activations from LDS, weights via wave-uniform s_loads.
__global__ __launch_bounds__(256) void k01_pack_conv1(
    const float* __restrict__ x,
    const int* __restrict__ w1p,
    const float* __restrict__ a1p, const float* __restrict__ o1p,
    int* __restrict__ x8p, int* __restrict__ y1p)
{
  __shared__ int ldsx[64 * 68];   // 17408 B

  int tid = threadIdx.x;

  // ---- Phase A: load + pack ----
  {
    int o = tid & 3;
    int p = tid >> 2;
    size_t pg = (size_t)blockIdx.x * 64 + p;   // global pos (n*HW + pos)
    int n = (int)(pg / HW);
    int pos = (int)(pg - (size_t)n * HW);
    const float* xb = x + ((size_t)n * 256 + o * 64) * HW + pos;

    float f[64];
#pragma unroll
    for (int k = 0; k < 64; ++k) f[k] = xb[(size_t)k * HW];
    __builtin_amdgcn_sched_barrier(0);  // all 64 loads before any consumer

    int4 ov[4];
#pragma unroll
    for (int g = 0; g < 4; ++g) {
      int wds[4];
#pragma unroll
      for (int wdi = 0; wdi < 4; ++wdi) {
        int c0 = g * 16 + wdi * 4;
        wds[wdi] = ((int)f[c0] & 0xFF) | (((int)f[c0 + 1] & 0xFF) << 8) |
                   (((int)f[c0 + 2] & 0xFF) << 16) | (((int)f[c0 + 3] & 0xFF) << 24);
      }
      ov[g].x = wds[0]; ov[g].y = wds[1]; ov[g].z = wds[2]; ov[g].w = wds[3];
    }

    int* gb = x8p + pg * 64 + o * 16;
#pragma unroll
    for (int g = 0; g < 4; ++g) ((int4*)gb)[g] = ov[g];
    int* lb = &ldsx[p * 68 + o * 16];
#pragma unroll
    for (int g = 0; g < 4; ++g) *(int4*)(lb + g * 4) = ov[g];
  }
  __syncthreads();

  // ---- Phase B: conv1 from LDS ----
  int lane = tid & 63;
  int s = __builtin_amdgcn_readfirstlane(tid >> 6);
  size_t pidx = (size_t)blockIdx.x * 64 + lane;

  int acc[16];
#pragma unroll
  for (int i = 0; i < 16; ++i) acc[i] = 0;

  const int* lx = &ldsx[lane * 68];
#pragma unroll
  for (int m = 0; m < 16; ++m) {
    int4 xm = *(const int4*)(lx + m * 4);
#pragma unroll
    for (int e = 0; e < 4; ++e) {
      int xv = e == 0 ? xm.x : (e == 1 ? xm.y : (e == 2 ? xm.z : xm.w));
      int cg = m * 4 + e;
      const int4* wr = (const int4*)(w1p + cg * 64 + s * 16);
#pragma unroll
      for (int c = 0; c < 4; ++c) {
        int4 wv = wr[c];
        acc[c * 4 + 0] = dot4i8(xv, wv.x, acc[c * 4 + 0]);
        acc[c * 4 + 1] = dot4i8(xv, wv.y, acc[c * 4 + 1]);
        acc[c * 4 + 2] = dot4i8(xv, wv.z, acc[c * 4 + 2]);
        acc[c * 4 + 3] = dot4i8(xv, wv.w, acc[c * 4 + 3]);
      }
    }
  }

  int op[4];
#pragma unroll
  for (int c = 0; c < 4; ++c) {
    int p = 0;
#pragma unroll
    for (int j = 0; j < 4; ++j) {
      int co = s * 16 + c * 4 + j;
      float r = bnq(a1p[co], o1p[co], acc[c * 4 + j]);
      int v = (int)r;
      if (v < 0) v = 0;  // relu
      p |= (v & 0xFF) << (8 * j);
    }
    op[c] = p;
  }
  int4 ov; ov.x = op[0]; ov.y = op[1]; ov.z = op[2]; ov.w = op[3];
  *(int4*)(y1p + pidx * 16 + s * 4) = ov;
}

// ---------------- k23: conv2 (LDS halo) -> y2 in LDS -> conv3 + residual ----------------
// Block = 64 consecutive positions (exactly 2 image rows; 3136 = 49*64).
// Stage zero-padded y1 halo [4 rows][58 cols][16 ints] -> conv2 with no masks
// -> y2 tile to LDS [64 pos][20-int padded row] -> conv3 + residual + out.
__global__ __launch_bounds__(256) void k23_conv23(
    const int* __restrict__ y1p,
    const int* __restrict__ w2p,   // [s][tap][cg][cc]
    const float* __restrict__ a2p, const float* __restrict__ o2p,
    const int* __restrict__ w3p,
    const float* __restrict__ a3p, const float* __restrict__ o3p,
    const int* __restrict__ x8p,
    float* __restrict__ out)
{
  __shared__ int4 lds[4 * 58 * 4];   // halo: 14848 B
  __shared__ int ldsy[64 * 20];      // y2 tile: 5120 B

  int lane = threadIdx.x & 63;
  int s = __builtin_amdgcn_readfirstlane(threadIdx.x >> 6);
  int p0 = blockIdx.x * 64;          // tile start (global pos units)
  int n = p0 / HW;
  int p0l = p0 - n * HW;
  int h0 = p0l / IMGW;

  // ---- stage halo: rows h0-1..h0+2, padded cols ----
  const int4* src = (const int4*)y1p;
  int tid = threadIdx.x;
#pragma unroll
  for (int i = 0; i < 4; ++i) {
    int idx = tid + i * 256;
    if (idx < 928) {
      int pp = idx >> 2;
      int chunk = idx & 3;
      int r = pp / 58;
      int col = pp - r * 58;
      int hh = h0 - 1 + r;
      int4 v = make_int4(0, 0, 0, 0);
      if ((unsigned)hh < 56u && col >= 1 && col <= 56) {
        v = src[((size_t)n * HW + (size_t)hh * IMGW + (col - 1)) * 4 + chunk];
      }
      lds[idx] = v;
    }
  }
  __syncthreads();

  int posl = p0l + lane;
  int h = posl / IMGW;
  int w = posl - h * IMGW;
  int center = (h - h0 + 1) * 58 + (w + 1);

  // ---- conv2 ----
  int acc[16];
#pragma unroll
  for (int i = 0; i < 16; ++i) acc[i] = 0;

  const int4* wq = (const int4*)w2p;

#pragma unroll
  for (int ky = 0; ky < 3; ++ky) {
#pragma unroll
    for (int kx = 0; kx < 3; ++kx) {
      int t = ky * 3 + kx;
      int lp2 = center + (ky - 1) * 58 + (kx - 1);
      const int4* xt = &lds[lp2 * 4];
      int4 x0 = xt[0], x1 = xt[1], x2 = xt[2], x3 = xt[3];
      const int4* wt = wq + (s * 9 + t) * 64;
#pragma unroll
      for (int m = 0; m < 4; ++m) {
        int4 xm = m == 0 ? x0 : (m == 1 ? x1 : (m == 2 ? x2 : x3));
#pragma unroll
        for (int e = 0; e < 4; ++e) {
          int xv = e == 0 ? xm.x : (e == 1 ? xm.y : (e == 2 ? xm.z : xm.w));
          const int4* wr = wt + (m * 4 + e) * 4;
#pragma unroll
          for (int cc = 0; cc < 4; ++cc) {
            int4 wv = wr[cc];
            acc[cc * 4 + 0] = dot4i8(xv, wv.x, acc[cc * 4 + 0]);
            acc[cc * 4 + 1] = dot4i8(xv, wv.y, acc[cc * 4 + 1]);
            acc[cc * 4 + 2] = dot4i8(xv, wv.z, acc[cc * 4 + 2]);
            acc[cc * 4 + 3] = dot4i8(xv, wv.w, acc[cc * 4 + 3]);
          }
        }
      }
    }
  }

  // BN+relu -> y2 tile in LDS (no global round-trip)
  {
    int op[4];
#pragma unroll
    for (int c = 0; c < 4; ++c) {
      int p = 0;
#pragma unroll
      for (int j = 0; j < 4; ++j) {
        int co = s * 16 + c * 4 + j;
        float r = bnq(a2p[co], o2p[co], acc[c * 4 + j]);
        int v = (int)r;
        if (v < 0) v = 0;
        p |= (v & 0xFF) << (8 * j);
      }
      op[c] = p;
    }
    int4 ov; ov.x = op[0]; ov.y = op[1]; ov.z = op[2]; ov.w = op[3];
    *(int4*)(&ldsy[lane * 20 + s * 4]) = ov;
  }
  __syncthreads();

  // ---- conv3 + residual + out; wave s -> out-ch s*64..s*64+63 ----
  size_t pidx = (size_t)p0 + lane;
  int pos = posl;

  int xp[16];
#pragma unroll
  for (int m = 0; m < 4; ++m) {
    int4 xm = *(const int4*)(&ldsy[lane * 20 + m * 4]);
    xp[m * 4 + 0] = xm.x;
    xp[m * 4 + 1] = xm.y;
    xp[m * 4 + 2] = xm.z;
    xp[m * 4 + 3] = xm.w;
  }

  const int4* rb4 = (const int4*)(x8p + pidx * 64 + s * 16);
  int rv[16];
#pragma unroll
  for (int m = 0; m < 4; ++m) {
    int4 rq = rb4[m];
    rv[m * 4 + 0] = rq.x;
    rv[m * 4 + 1] = rq.y;
    rv[m * 4 + 2] = rq.z;
    rv[m * 4 + 3] = rq.w;
  }

#pragma unroll
  for (int c4 = 0; c4 < 16; ++c4) {
    int co4 = s * 16 + c4;
    const int4* wr = ((const int4*)w3p) + co4 * 16;  // uniform -> s_load
    int ac0 = 0, ac1 = 0, ac2 = 0, ac3 = 0;
#pragma unroll
    for (int cg = 0; cg < 16; ++cg) {
      int4 wv = wr[cg];
      ac0 = dot4i8(xp[cg], wv.x, ac0);
      ac1 = dot4i8(xp[cg], wv.y, ac1);
      ac2 = dot4i8(xp[cg], wv.z, ac2);
      ac3 = dot4i8(xp[cg], wv.w, ac3);
    }

    int ip = rv[c4];
    int ids[4];
    ids[0] = (int)(int8_t)(ip);
    ids[1] = (int)(int8_t)(ip >> 8);
    ids[2] = (int)(int8_t)(ip >> 16);
    ids[3] = (int)(int8_t)(ip >> 24);

    float* ob = out + ((size_t)n * 256 + (size_t)co4 * 4) * HW + pos;
    int accs[4] = {ac0, ac1, ac2, ac3};
#pragma unroll
    for (int j = 0; j < 4; ++j) {
      int co = co4 * 4 + j;
      float r = bnq(a3p[co], o3p[co], accs[j]);
      int v = (int)r + ids[j];
      v = v > 127 ? 127 : v;
      v = v < 0 ? 0 : v;  // clamp(-128,..) then relu => max(0, min(127, .))
      ob[(size_t)j * HW] = (float)v;
    }
  }
}

extern "C" void kernel_launch(void* const* d_in, const int* in_sizes, int n_in,
                              void* d_out, int out_size, void* d_ws, size_t ws_size,
                              hipStream_t stream) {
  const float* x  = (const float*)d_in[0];
  const int*   s1 = (const int*)d_in[1];
  const int*   m1 = (const int*)d_in[2];
  const float* a1 = (const float*)d_in[3];
  const float* b1 = (const float*)d_in[4];
  const int*   q1 = (const int*)d_in[5];
  const int*   s2 = (const int*)d_in[6];
  const int*   m2 = (const int*)d_in[7];
  const float* a2 = (const float*)d_in[8];
  const float* b2 = (const float*)d_in[9];
  const int*   q2 = (const int*)d_in[10];
  const int*   s3 = (const int*)d_in[11];
  const int*   m3 = (const int*)d_in[12];
  const float* a3 = (const float*)d_in[13];
  const float* b3 = (const float*)d_in[14];
  const int*   q3 = (const int*)d_in[15];

  char* ws = (char*)d_ws;
  int* w1p = (int*)(ws + 0);        // 16384 B
  int* w2p = (int*)(ws + 16384);    // 36864 B
  int* w3p = (int*)(ws + 53248);    // 16384 B
  float* a1p = (float*)(ws + 69632);
  float* o1p = (float*)(ws + 69888);
  float* a2p = (float*)(ws + 70144);
  float* o2p = (float*)(ws + 70400);
  float* a3p = (float*)(ws + 70656);
  float* o3p = (float*)(ws + 71680);
  int* y1p = (int*)(ws + 73728);                       // 6,422,528 B (packed [n][pos][16])
  int* x8p = (int*)(ws + 73728 + 6422528);             // 25,690,112 B (packed [n][pos][64])

  prep_kernel<<<64, 256, 0, stream>>>(s1, m1, a1, b1, q1,
                                      s2, m2, a2, b2, q2,
                                      s3, m3, a3, b3, q3,
                                      w1p, w2p, w3p,
                                      a1p, o1p, a2p, o2p, a3p, o3p);

  const int grid = (NIMG * HW) / 64;  // 1568 blocks
  k01_pack_conv1<<<grid, 256, 0, stream>>>(x, w1p, a1p, o1p, x8p, y1p);
  k23_conv23<<<grid, 256, 0, stream>>>(y1p, w2p, a2p, o2p,
                                       w3p, a3p, o3p, x8p,
                                       (float*)d_out);
}